// Round 1
// baseline (459.512 us; speedup 1.0000x reference)
//
#include <hip/hip_runtime.h>

// ---------------------------------------------------------------------------
// AttnBlock: GroupNorm -> QKV 1x1conv -> spatial attention (HW=4096, D=512)
//            -> out 1x1conv + residual.  B=4, C=512, H=W=64, fp32 in/out.
// Strategy: all GEMMs in f16 MFMA (fp32 accum), gemm_bt layout everywhere.
// ---------------------------------------------------------------------------

typedef _Float16 f16;
typedef _Float16 f16x8 __attribute__((ext_vector_type(8)));
typedef float f32x4 __attribute__((ext_vector_type(4)));

#define BATCH 4
#define CCH 512
#define HW 4096
#define NGRP 32

__device__ __forceinline__ void load_lds16(const void* g, void* l) {
  __builtin_amdgcn_global_load_lds(
      (const __attribute__((address_space(1))) unsigned int*)g,
      (__attribute__((address_space(3))) unsigned int*)l, 16, 0, 0);
}

__device__ __forceinline__ f32x4 mfma16(f16x8 a, f16x8 b, f32x4 c) {
  return __builtin_amdgcn_mfma_f32_16x16x32_f16(a, b, c, 0, 0, 0);
}

// ---------------------------------------------------------------------------
// Weight prep: W_qk (1024x512) f16 with q rows pre-scaled by 1/sqrt(512),
// b_qk f32 (1024, q part scaled), W_v f16, W_o f16.
// ---------------------------------------------------------------------------
__global__ __launch_bounds__(256) void prep_weights(
    const float* __restrict__ wq, const float* __restrict__ bq,
    const float* __restrict__ wk, const float* __restrict__ bk,
    const float* __restrict__ wv, const float* __restrict__ wo,
    f16* __restrict__ Wqk, float* __restrict__ bqk,
    f16* __restrict__ Wv, f16* __restrict__ Wo) {
  const float s = 0.04419417382415922f;  // 1/sqrt(512)
  int i = blockIdx.x * 256 + threadIdx.x;  // grid covers 1048576
  if (i < 524288) {
    int row = i >> 9;
    Wqk[i] = (f16)((row < 512) ? wq[i] * s : wk[i - 262144]);
  } else if (i < 786432) {
    Wv[i - 524288] = (f16)wv[i - 524288];
  } else if (i < 1048576) {
    Wo[i - 786432] = (f16)wo[i - 786432];
  }
  if (i < 1024) bqk[i] = (i < 512) ? bq[i] * s : bk[i - 512];
}

// ---------------------------------------------------------------------------
// GroupNorm stats: one block per (b, group): 16 ch x 4096 = 65536 contiguous
// floats.  stats[bg] = (mean, rstd)
// ---------------------------------------------------------------------------
__global__ __launch_bounds__(256) void gn_stats(const float* __restrict__ x,
                                                float2* __restrict__ stats) {
  long base = (long)blockIdx.x * 65536;
  int tid = threadIdx.x;
  float s = 0.f, ss = 0.f;
  for (int i = tid; i < 16384; i += 256) {
    float4 v = *(const float4*)&x[base + (long)i * 4];
    s += v.x + v.y + v.z + v.w;
    ss += v.x * v.x + v.y * v.y + v.z * v.z + v.w * v.w;
  }
#pragma unroll
  for (int o = 32; o; o >>= 1) {
    s += __shfl_xor(s, o);
    ss += __shfl_xor(ss, o);
  }
  __shared__ float rs[4], rss[4];
  if ((tid & 63) == 0) { rs[tid >> 6] = s; rss[tid >> 6] = ss; }
  __syncthreads();
  if (tid == 0) {
    s = rs[0] + rs[1] + rs[2] + rs[3];
    ss = rss[0] + rss[1] + rss[2] + rss[3];
    float mean = s * (1.f / 65536.f);
    float var = ss * (1.f / 65536.f) - mean * mean;
    stats[blockIdx.x] = make_float2(mean, rsqrtf(var + 1e-5f));
  }
}

// ---------------------------------------------------------------------------
// GroupNorm apply + transpose: x (B,C,HW) f32 -> h_t (B,HW,C) f16.
// Block handles 64 positions x all 512 channels via LDS transpose.
// ---------------------------------------------------------------------------
__global__ __launch_bounds__(256) void gn_apply(
    const float* __restrict__ x, const float2* __restrict__ stats,
    const float* __restrict__ gnw, const float* __restrict__ gnb,
    f16* __restrict__ h_t) {
  int b = blockIdx.x >> 6;
  int p0 = (blockIdx.x & 63) * 64;
  int tid = threadIdx.x;
  __shared__ __align__(16) f16 lds[64 * 520];  // pad 512->520 (16B-aligned rows)
  int c0 = tid >> 4;   // 0..15
  int p4 = tid & 15;   // float4 index
  for (int it = 0; it < 32; ++it) {
    int c = it * 16 + c0;
    float2 st = stats[b * 32 + (c >> 4)];
    float a = st.y * gnw[c];
    float sh = gnb[c] - st.x * a;
    float4 v = *(const float4*)&x[((long)(b * 512 + c)) * 4096 + p0 + p4 * 4];
    int pr = p4 * 4;
    lds[(pr + 0) * 520 + c] = (f16)(v.x * a + sh);
    lds[(pr + 1) * 520 + c] = (f16)(v.y * a + sh);
    lds[(pr + 2) * 520 + c] = (f16)(v.z * a + sh);
    lds[(pr + 3) * 520 + c] = (f16)(v.w * a + sh);
  }
  __syncthreads();
  for (int it = 0; it < 16; ++it) {
    int cid = it * 256 + tid;
    int prow = cid >> 6, c8 = (cid & 63) * 8;
    *(f16x8*)&h_t[((long)(b * 4096 + p0 + prow)) * 512 + c8] =
        *(const f16x8*)&lds[prow * 520 + c8];
  }
}

// ---------------------------------------------------------------------------
// gemm_bt: C[m][n] = sum_k A[m][k] * B[n][k]  (both K-contiguous), f16 in,
// fp32 accum.  128x128 tile, 4 waves, BK=32, global_load_lds staging (m97).
// MODE 0: f16 out + col-bias     (QK projection)
// MODE 1: f16 out + row-bias     (V projection)
// MODE 2: f16 out, plain         (S and PV)
// MODE 3: f32 out + row-bias + residual  (final projection)
// ---------------------------------------------------------------------------
template <int MODE>
__global__ __launch_bounds__(256) void gemm_bt(
    const f16* __restrict__ A, int lda, long sAz,
    const f16* __restrict__ B, int ldb, long sBz,
    void* __restrict__ C, int ldc, long sCz,
    const float* __restrict__ bias,
    const float* __restrict__ resid, long sRz,
    int M, int N, int K) {
  __shared__ __align__(16) f16 tA[4096];  // [128][32]
  __shared__ __align__(16) f16 tB[4096];
  const f16* Az = A + (long)blockIdx.z * sAz;
  const f16* Bz = B + (long)blockIdx.z * sBz;
  int tid = threadIdx.x, lane = tid & 63, wid = tid >> 6;
  long bm = (long)blockIdx.x * 128, bn = (long)blockIdx.y * 128;
  int srow = lane >> 2, scol = (lane & 3) * 8;
  int wrow = (wid >> 1) * 64, wcol = (wid & 1) * 64;
  int r = lane & 15, kb = (lane >> 4) * 8;

  const f16* gA0 = Az + (bm + wid * 32 + srow) * (long)lda + scol;
  const f16* gA1 = gA0 + 16 * (long)lda;
  const f16* gB0 = Bz + (bn + wid * 32 + srow) * (long)ldb + scol;
  const f16* gB1 = gB0 + 16 * (long)ldb;
  f16* lA0 = &tA[wid * 1024];
  f16* lA1 = &tA[wid * 1024 + 512];
  f16* lB0 = &tB[wid * 1024];
  f16* lB1 = &tB[wid * 1024 + 512];

  f32x4 acc[4][4];
#pragma unroll
  for (int i = 0; i < 4; ++i)
#pragma unroll
    for (int j = 0; j < 4; ++j) acc[i][j] = (f32x4){0.f, 0.f, 0.f, 0.f};

  for (int kt = 0; kt < K; kt += 32) {
    load_lds16(gA0 + kt, lA0);
    load_lds16(gA1 + kt, lA1);
    load_lds16(gB0 + kt, lB0);
    load_lds16(gB1 + kt, lB1);
    __syncthreads();  // drains vmcnt -> staged data visible
    f16x8 af[4], bfr[4];
#pragma unroll
    for (int mf = 0; mf < 4; ++mf)
      af[mf] = *(const f16x8*)&tA[(wrow + mf * 16 + r) * 32 + kb];
#pragma unroll
    for (int nf = 0; nf < 4; ++nf)
      bfr[nf] = *(const f16x8*)&tB[(wcol + nf * 16 + r) * 32 + kb];
#pragma unroll
    for (int mf = 0; mf < 4; ++mf)
#pragma unroll
      for (int nf = 0; nf < 4; ++nf)
        acc[mf][nf] = mfma16(af[mf], bfr[nf], acc[mf][nf]);
    __syncthreads();  // protect LDS before next stage
  }

  long zC = (long)blockIdx.z * sCz;
  int r0 = (lane >> 4) * 4, cc = lane & 15;
#pragma unroll
  for (int mf = 0; mf < 4; ++mf) {
#pragma unroll
    for (int nf = 0; nf < 4; ++nf) {
      long gr = bm + wrow + mf * 16 + r0;
      long gc = bn + wcol + nf * 16 + cc;
#pragma unroll
      for (int rr = 0; rr < 4; ++rr) {
        float v = acc[mf][nf][rr];
        long R = gr + rr;
        if constexpr (MODE == 0) v += bias[gc];
        if constexpr (MODE == 1) v += bias[R];
        if constexpr (MODE == 3)
          v += bias[R] + resid[(long)blockIdx.z * sRz + R * (long)ldc + gc];
        long idx = zC + R * (long)ldc + gc;
        if constexpr (MODE == 3)
          ((float*)C)[idx] = v;
        else
          ((f16*)C)[idx] = (f16)v;
      }
    }
  }
}

// ---------------------------------------------------------------------------
// Row softmax, in place on f16 S. One block per row of 4096.
// ---------------------------------------------------------------------------
__global__ __launch_bounds__(256) void softmax_rows(f16* __restrict__ S) {
  long row = blockIdx.x;
  f16* p = S + row * 4096;
  int tid = threadIdx.x;
  f16x8 a = *(const f16x8*)&p[tid * 8];
  f16x8 b = *(const f16x8*)&p[2048 + tid * 8];
  float v[16];
#pragma unroll
  for (int j = 0; j < 8; ++j) { v[j] = (float)a[j]; v[8 + j] = (float)b[j]; }
  float m = v[0];
#pragma unroll
  for (int j = 1; j < 16; ++j) m = fmaxf(m, v[j]);
#pragma unroll
  for (int o = 32; o; o >>= 1) m = fmaxf(m, __shfl_xor(m, o));
  __shared__ float red[8];
  if ((tid & 63) == 0) red[tid >> 6] = m;
  __syncthreads();
  m = fmaxf(fmaxf(red[0], red[1]), fmaxf(red[2], red[3]));
  float s = 0.f;
  float e[16];
#pragma unroll
  for (int j = 0; j < 16; ++j) { e[j] = __expf(v[j] - m); s += e[j]; }
#pragma unroll
  for (int o = 32; o; o >>= 1) s += __shfl_xor(s, o);
  if ((tid & 63) == 0) red[4 + (tid >> 6)] = s;
  __syncthreads();
  s = red[4] + red[5] + red[6] + red[7];
  float inv = 1.f / s;
#pragma unroll
  for (int j = 0; j < 8; ++j) {
    a[j] = (f16)(e[j] * inv);
    b[j] = (f16)(e[8 + j] * inv);
  }
  *(f16x8*)&p[tid * 8] = a;
  *(f16x8*)&p[2048 + tid * 8] = b;
}

// ---------------------------------------------------------------------------
extern "C" void kernel_launch(void* const* d_in, const int* in_sizes, int n_in,
                              void* d_out, int out_size, void* d_ws,
                              size_t ws_size, hipStream_t stream) {
  (void)in_sizes; (void)n_in; (void)out_size;
  const float* x   = (const float*)d_in[0];
  const float* gnw = (const float*)d_in[1];
  const float* gnb = (const float*)d_in[2];
  const float* wq  = (const float*)d_in[3];
  const float* bq  = (const float*)d_in[4];
  const float* wk  = (const float*)d_in[5];
  const float* bk  = (const float*)d_in[6];
  const float* wv  = (const float*)d_in[7];
  const float* bv  = (const float*)d_in[8];
  const float* wo  = (const float*)d_in[9];
  const float* bo  = (const float*)d_in[10];
  float* out = (float*)d_out;

  char* p = (char*)d_ws;
  auto alloc = [&](size_t bytes) {
    char* r = p;
    p += (bytes + 255) & ~(size_t)255;
    return r;
  };
  f16* Wqk    = (f16*)alloc(1024 * 512 * 2);
  float* bqk  = (float*)alloc(1024 * 4);
  f16* Wv     = (f16*)alloc(512 * 512 * 2);
  f16* Wo     = (f16*)alloc(512 * 512 * 2);
  float2* st  = (float2*)alloc(128 * 8);
  f16* h_t    = (f16*)alloc(16384L * 512 * 2);   // (B,HW,C)
  f16* qk_t   = (f16*)alloc(16384L * 1024 * 2);  // q_t cols 0-511, k_t 512-1023
  f16* v_ws   = (f16*)alloc(512L * 16384 * 2);   // (C, B*HW)
  f16* o_t    = (f16*)alloc(16384L * 512 * 2);   // (B,HW,C)
  size_t used = (size_t)(p - (char*)d_ws);
  long sfull = 4L * 4096 * 4096 * 2;
  int nb = (ws_size >= used + (size_t)sfull) ? 4 : 1;
  f16* S = (f16*)alloc((size_t)nb * 4096L * 4096 * 2);

  prep_weights<<<4096, 256, 0, stream>>>(wq, bq, wk, bk, wv, wo, Wqk, bqk, Wv, Wo);
  gn_stats<<<128, 256, 0, stream>>>(x, st);
  gn_apply<<<256, 256, 0, stream>>>(x, st, gnw, gnb, h_t);

  // q_t / k_t:  (16384 x 1024) = h_t (16384x512) . Wqk^T
  gemm_bt<0><<<dim3(128, 8, 1), 256, 0, stream>>>(
      h_t, 512, 0, Wqk, 512, 0, qk_t, 1024, 0, bqk, nullptr, 0, 16384, 1024, 512);
  // v: (512 x 16384) = Wv . h_t^T
  gemm_bt<1><<<dim3(4, 128, 1), 256, 0, stream>>>(
      Wv, 512, 0, h_t, 512, 0, v_ws, 16384, 0, bv, nullptr, 0, 512, 16384, 512);

  if (nb == 4) {
    gemm_bt<2><<<dim3(32, 32, 4), 256, 0, stream>>>(
        qk_t, 1024, 4096L * 1024, qk_t + 512, 1024, 4096L * 1024,
        S, 4096, 4096L * 4096, nullptr, nullptr, 0, 4096, 4096, 512);
    softmax_rows<<<16384, 256, 0, stream>>>(S);
    gemm_bt<2><<<dim3(32, 4, 4), 256, 0, stream>>>(
        S, 4096, 4096L * 4096, v_ws, 16384, 4096,
        o_t, 512, 4096L * 512, nullptr, nullptr, 0, 4096, 512, 4096);
  } else {
    for (int b = 0; b < 4; ++b) {
      gemm_bt<2><<<dim3(32, 32, 1), 256, 0, stream>>>(
          qk_t + (long)b * 4096 * 1024, 1024, 0,
          qk_t + 512 + (long)b * 4096 * 1024, 1024, 0,
          S, 4096, 0, nullptr, nullptr, 0, 4096, 4096, 512);
      softmax_rows<<<4096, 256, 0, stream>>>(S);
      gemm_bt<2><<<dim3(32, 4, 1), 256, 0, stream>>>(
          S, 4096, 0, v_ws + (long)b * 4096, 16384, 0,
          o_t + (long)b * 4096 * 512, 512, 0, nullptr, nullptr, 0,
          4096, 512, 4096);
    }
  }

  // out = x + Wo . o_t^T + bo   (per batch, f32)
  gemm_bt<3><<<dim3(4, 32, 4), 256, 0, stream>>>(
      Wo, 512, 0, o_t, 512, 4096L * 512, out, 4096, 512L * 4096,
      bo, x, 512L * 4096, 512, 4096, 512);
}

// Round 3
// 444.303 us; speedup vs baseline: 1.0342x; 1.0342x over previous
//
#include <hip/hip_runtime.h>

// ---------------------------------------------------------------------------
// AttnBlock: GroupNorm -> QKV 1x1conv -> spatial attention (HW=4096, D=512)
//            -> out 1x1conv + residual.  B=4, C=512, H=W=64, fp32 in/out.
// All GEMMs f16 MFMA (fp32 accum), gemm_bt layout everywhere.
// R2: max-free softmax fused into S-gemm epilogue (exp + row-sum atomics);
//     PV normalizes by 1/l in its epilogue; PV re-tiled 64x128 for occupancy.
// ---------------------------------------------------------------------------

typedef _Float16 f16;
typedef _Float16 f16x8 __attribute__((ext_vector_type(8)));
typedef float f32x4 __attribute__((ext_vector_type(4)));

__device__ __forceinline__ void load_lds16(const void* g, void* l) {
  __builtin_amdgcn_global_load_lds(
      (const __attribute__((address_space(1))) unsigned int*)g,
      (__attribute__((address_space(3))) unsigned int*)l, 16, 0, 0);
}

__device__ __forceinline__ f32x4 mfma16(f16x8 a, f16x8 b, f32x4 c) {
  return __builtin_amdgcn_mfma_f32_16x16x32_f16(a, b, c, 0, 0, 0);
}

// ---------------------------------------------------------------------------
// Weight prep + l zeroing.
// ---------------------------------------------------------------------------
__global__ __launch_bounds__(256) void prep_weights(
    const float* __restrict__ wq, const float* __restrict__ bq,
    const float* __restrict__ wk, const float* __restrict__ bk,
    const float* __restrict__ wv, const float* __restrict__ wo,
    f16* __restrict__ Wqk, float* __restrict__ bqk,
    f16* __restrict__ Wv, f16* __restrict__ Wo, float* __restrict__ lsum) {
  const float s = 0.04419417382415922f;  // 1/sqrt(512)
  int i = blockIdx.x * 256 + threadIdx.x;  // grid covers 1048576
  if (i < 524288) {
    int row = i >> 9;
    Wqk[i] = (f16)((row < 512) ? wq[i] * s : wk[i - 262144]);
  } else if (i < 786432) {
    Wv[i - 524288] = (f16)wv[i - 524288];
  } else if (i < 1048576) {
    Wo[i - 786432] = (f16)wo[i - 786432];
  }
  if (i < 1024) bqk[i] = (i < 512) ? bq[i] * s : bk[i - 512];
  if (i < 16384) lsum[i] = 0.f;
}

// ---------------------------------------------------------------------------
// GroupNorm stats: one block per (b, group).
// ---------------------------------------------------------------------------
__global__ __launch_bounds__(256) void gn_stats(const float* __restrict__ x,
                                                float2* __restrict__ stats) {
  long base = (long)blockIdx.x * 65536;
  int tid = threadIdx.x;
  float s = 0.f, ss = 0.f;
  for (int i = tid; i < 16384; i += 256) {
    float4 v = *(const float4*)&x[base + (long)i * 4];
    s += v.x + v.y + v.z + v.w;
    ss += v.x * v.x + v.y * v.y + v.z * v.z + v.w * v.w;
  }
#pragma unroll
  for (int o = 32; o; o >>= 1) {
    s += __shfl_xor(s, o);
    ss += __shfl_xor(ss, o);
  }
  __shared__ float rs[4], rss[4];
  if ((tid & 63) == 0) { rs[tid >> 6] = s; rss[tid >> 6] = ss; }
  __syncthreads();
  if (tid == 0) {
    s = rs[0] + rs[1] + rs[2] + rs[3];
    ss = rss[0] + rss[1] + rss[2] + rss[3];
    float mean = s * (1.f / 65536.f);
    float var = ss * (1.f / 65536.f) - mean * mean;
    stats[blockIdx.x] = make_float2(mean, rsqrtf(var + 1e-5f));
  }
}

// ---------------------------------------------------------------------------
// GroupNorm apply + transpose: x (B,C,HW) f32 -> h_t (B,HW,C) f16.
// ---------------------------------------------------------------------------
__global__ __launch_bounds__(256) void gn_apply(
    const float* __restrict__ x, const float2* __restrict__ stats,
    const float* __restrict__ gnw, const float* __restrict__ gnb,
    f16* __restrict__ h_t) {
  int b = blockIdx.x >> 6;
  int p0 = (blockIdx.x & 63) * 64;
  int tid = threadIdx.x;
  __shared__ __align__(16) f16 lds[64 * 520];
  int c0 = tid >> 4;
  int p4 = tid & 15;
  for (int it = 0; it < 32; ++it) {
    int c = it * 16 + c0;
    float2 st = stats[b * 32 + (c >> 4)];
    float a = st.y * gnw[c];
    float sh = gnb[c] - st.x * a;
    float4 v = *(const float4*)&x[((long)(b * 512 + c)) * 4096 + p0 + p4 * 4];
    int pr = p4 * 4;
    lds[(pr + 0) * 520 + c] = (f16)(v.x * a + sh);
    lds[(pr + 1) * 520 + c] = (f16)(v.y * a + sh);
    lds[(pr + 2) * 520 + c] = (f16)(v.z * a + sh);
    lds[(pr + 3) * 520 + c] = (f16)(v.w * a + sh);
  }
  __syncthreads();
  for (int it = 0; it < 16; ++it) {
    int cid = it * 256 + tid;
    int prow = cid >> 6, c8 = (cid & 63) * 8;
    *(f16x8*)&h_t[((long)(b * 4096 + p0 + prow)) * 512 + c8] =
        *(const f16x8*)&lds[prow * 520 + c8];
  }
}

// ---------------------------------------------------------------------------
// gemm_bt: C[m][n] = sum_k A[m][k]*B[n][k], f16 in, fp32 accum, 128x128 tile.
// MODE 0: f16 out + col-bias                (QK projection)
// MODE 1: f16 out + row-bias                (V projection)
// MODE 2: f16 out = exp(v), row-sums -> lsum (attention scores)
// MODE 3: f32 out + row-bias + residual     (final projection)
// ---------------------------------------------------------------------------
template <int MODE>
__global__ __launch_bounds__(256) void gemm_bt(
    const f16* __restrict__ A, int lda, long sAz,
    const f16* __restrict__ B, int ldb, long sBz,
    void* __restrict__ C, int ldc, long sCz,
    const float* __restrict__ bias, float* __restrict__ lsum,
    const float* __restrict__ resid, long sRz,
    int M, int N, int K) {
  __shared__ __align__(16) f16 tA[4096];  // [128][32]
  __shared__ __align__(16) f16 tB[4096];
  const f16* Az = A + (long)blockIdx.z * sAz;
  const f16* Bz = B + (long)blockIdx.z * sBz;
  int tid = threadIdx.x, lane = tid & 63, wid = tid >> 6;
  long bm = (long)blockIdx.x * 128, bn = (long)blockIdx.y * 128;
  int srow = lane >> 2, scol = (lane & 3) * 8;
  int wrow = (wid >> 1) * 64, wcol = (wid & 1) * 64;
  int r = lane & 15, kb = (lane >> 4) * 8;

  const f16* gA0 = Az + (bm + wid * 32 + srow) * (long)lda + scol;
  const f16* gA1 = gA0 + 16 * (long)lda;
  const f16* gB0 = Bz + (bn + wid * 32 + srow) * (long)ldb + scol;
  const f16* gB1 = gB0 + 16 * (long)ldb;
  f16* lA0 = &tA[wid * 1024];
  f16* lA1 = &tA[wid * 1024 + 512];
  f16* lB0 = &tB[wid * 1024];
  f16* lB1 = &tB[wid * 1024 + 512];

  f32x4 acc[4][4];
#pragma unroll
  for (int i = 0; i < 4; ++i)
#pragma unroll
    for (int j = 0; j < 4; ++j) acc[i][j] = (f32x4){0.f, 0.f, 0.f, 0.f};

  for (int kt = 0; kt < K; kt += 32) {
    load_lds16(gA0 + kt, lA0);
    load_lds16(gA1 + kt, lA1);
    load_lds16(gB0 + kt, lB0);
    load_lds16(gB1 + kt, lB1);
    __syncthreads();
    f16x8 af[4], bfr[4];
#pragma unroll
    for (int mf = 0; mf < 4; ++mf)
      af[mf] = *(const f16x8*)&tA[(wrow + mf * 16 + r) * 32 + kb];
#pragma unroll
    for (int nf = 0; nf < 4; ++nf)
      bfr[nf] = *(const f16x8*)&tB[(wcol + nf * 16 + r) * 32 + kb];
#pragma unroll
    for (int mf = 0; mf < 4; ++mf)
#pragma unroll
      for (int nf = 0; nf < 4; ++nf)
        acc[mf][nf] = mfma16(af[mf], bfr[nf], acc[mf][nf]);
    __syncthreads();
  }

  long zC = (long)blockIdx.z * sCz;
  int r0 = (lane >> 4) * 4, cc = lane & 15;
#pragma unroll
  for (int mf = 0; mf < 4; ++mf) {
#pragma unroll
    for (int rr = 0; rr < 4; ++rr) {
      long R = bm + wrow + mf * 16 + r0 + rr;
      float badd = 0.f, rowsum = 0.f;
      if constexpr (MODE == 1 || MODE == 3) badd = bias[R];
#pragma unroll
      for (int nf = 0; nf < 4; ++nf) {
        long gc = bn + wcol + nf * 16 + cc;
        float v = acc[mf][nf][rr];
        if constexpr (MODE == 0) v += bias[gc];
        if constexpr (MODE == 1) v += badd;
        if constexpr (MODE == 2) { v = __expf(fminf(v, 11.f)); rowsum += v; }
        if constexpr (MODE == 3)
          v += badd + resid[(long)blockIdx.z * sRz + R * (long)ldc + gc];
        long idx = zC + R * (long)ldc + gc;
        if constexpr (MODE == 3)
          ((float*)C)[idx] = v;
        else
          ((f16*)C)[idx] = (f16)v;
      }
      if constexpr (MODE == 2) {
        rowsum += __shfl_xor(rowsum, 1);
        rowsum += __shfl_xor(rowsum, 2);
        rowsum += __shfl_xor(rowsum, 4);
        rowsum += __shfl_xor(rowsum, 8);
        if (cc == 0) atomicAdd(&lsum[(long)blockIdx.z * 4096 + R], rowsum);
      }
    }
  }
}

// ---------------------------------------------------------------------------
// pv_gemm: O[m][n] = (1/l[m]) * sum_k P[m][k] * V[n][k].  64x128 tile,
// 4 waves (each wave one 64x32 column slab), K=4096.  Grid (64, 4, B).
// ---------------------------------------------------------------------------
__global__ __launch_bounds__(256) void pv_gemm(
    const f16* __restrict__ P, long sPz,
    const f16* __restrict__ V, long sVz,
    const float* __restrict__ lsum, int lzs,
    f16* __restrict__ O, long sOz) {
  __shared__ __align__(16) f16 tA[2048];  // [64][32]
  __shared__ __align__(16) f16 tB[4096];  // [128][32]
  const f16* Az = P + (long)blockIdx.z * sPz;
  const f16* Bz = V + (long)blockIdx.z * sVz;
  int tid = threadIdx.x, lane = tid & 63, wid = tid >> 6;
  long bm = (long)blockIdx.x * 64, bn = (long)blockIdx.y * 128;
  int srow = lane >> 2, scol = (lane & 3) * 8;
  int r = lane & 15, kb = (lane >> 4) * 8;

  const f16* gA0 = Az + (bm + wid * 16 + srow) * 4096L + scol;
  const f16* gB0 = Bz + (bn + wid * 32 + srow) * 16384L + scol;
  const f16* gB1 = gB0 + 16 * 16384L;
  f16* lA0 = &tA[wid * 512];
  f16* lB0 = &tB[wid * 1024];
  f16* lB1 = &tB[wid * 1024 + 512];

  f32x4 acc[4][2];
#pragma unroll
  for (int i = 0; i < 4; ++i)
#pragma unroll
    for (int j = 0; j < 2; ++j) acc[i][j] = (f32x4){0.f, 0.f, 0.f, 0.f};

  for (int kt = 0; kt < 4096; kt += 32) {
    load_lds16(gA0 + kt, lA0);
    load_lds16(gB0 + kt, lB0);
    load_lds16(gB1 + kt, lB1);
    __syncthreads();
    f16x8 af[4], bfr[2];
#pragma unroll
    for (int mf = 0; mf < 4; ++mf)
      af[mf] = *(const f16x8*)&tA[(mf * 16 + r) * 32 + kb];
#pragma unroll
    for (int nf = 0; nf < 2; ++nf)
      bfr[nf] = *(const f16x8*)&tB[(wid * 32 + nf * 16 + r) * 32 + kb];
#pragma unroll
    for (int mf = 0; mf < 4; ++mf)
#pragma unroll
      for (int nf = 0; nf < 2; ++nf)
        acc[mf][nf] = mfma16(af[mf], bfr[nf], acc[mf][nf]);
    __syncthreads();
  }

  int r0 = (lane >> 4) * 4, cc = lane & 15;
#pragma unroll
  for (int mf = 0; mf < 4; ++mf) {
#pragma unroll
    for (int rr = 0; rr < 4; ++rr) {
      long R = bm + mf * 16 + r0 + rr;
      float linv = 1.0f / lsum[(long)blockIdx.z * lzs + R];
#pragma unroll
      for (int nf = 0; nf < 2; ++nf) {
        long gc = bn + wid * 32 + nf * 16 + cc;
        O[(long)blockIdx.z * sOz + R * 512 + gc] =
            (f16)(acc[mf][nf][rr] * linv);
      }
    }
  }
}

// ---------------------------------------------------------------------------
extern "C" void kernel_launch(void* const* d_in, const int* in_sizes, int n_in,
                              void* d_out, int out_size, void* d_ws,
                              size_t ws_size, hipStream_t stream) {
  (void)in_sizes; (void)n_in; (void)out_size;
  const float* x   = (const float*)d_in[0];
  const float* gnw = (const float*)d_in[1];
  const float* gnb = (const float*)d_in[2];
  const float* wq  = (const float*)d_in[3];
  const float* bq  = (const float*)d_in[4];
  const float* wk  = (const float*)d_in[5];
  const float* bk  = (const float*)d_in[6];
  const float* wv  = (const float*)d_in[7];
  const float* bv  = (const float*)d_in[8];
  const float* wo  = (const float*)d_in[9];
  const float* bo  = (const float*)d_in[10];
  float* out = (float*)d_out;

  char* p = (char*)d_ws;
  auto alloc = [&](size_t bytes) {
    char* r = p;
    p += (bytes + 255) & ~(size_t)255;
    return r;
  };
  f16* Wqk    = (f16*)alloc(1024 * 512 * 2);
  float* bqk  = (float*)alloc(1024 * 4);
  f16* Wv     = (f16*)alloc(512 * 512 * 2);
  f16* Wo     = (f16*)alloc(512 * 512 * 2);
  float2* st  = (float2*)alloc(128 * 8);
  f16* h_t    = (f16*)alloc(16384L * 512 * 2);   // (B,HW,C)
  f16* qk_t   = (f16*)alloc(16384L * 1024 * 2);  // q_t cols 0-511, k_t 512-1023
  f16* v_ws   = (f16*)alloc(512L * 16384 * 2);   // (C, B*HW)
  f16* o_t    = (f16*)alloc(16384L * 512 * 2);   // (B,HW,C)
  float* lsum = (float*)alloc(16384L * 4);       // row sums of exp(S)
  size_t used = (size_t)(p - (char*)d_ws);
  long sfull = 4L * 4096 * 4096 * 2;
  int nb = (ws_size >= used + (size_t)sfull) ? 4 : 1;
  f16* S = (f16*)alloc((size_t)nb * 4096L * 4096 * 2);

  prep_weights<<<4096, 256, 0, stream>>>(wq, bq, wk, bk, wv, wo, Wqk, bqk, Wv,
                                         Wo, lsum);
  gn_stats<<<128, 256, 0, stream>>>(x, st);
  gn_apply<<<256, 256, 0, stream>>>(x, st, gnw, gnb, h_t);

  // q_t / k_t:  (16384 x 1024) = h_t (16384x512) . Wqk^T
  gemm_bt<0><<<dim3(128, 8, 1), 256, 0, stream>>>(
      h_t, 512, 0, Wqk, 512, 0, qk_t, 1024, 0, bqk, nullptr, nullptr, 0,
      16384, 1024, 512);
  // v: (512 x 16384) = Wv . h_t^T
  gemm_bt<1><<<dim3(4, 128, 1), 256, 0, stream>>>(
      Wv, 512, 0, h_t, 512, 0, v_ws, 16384, 0, bv, nullptr, nullptr, 0,
      512, 16384, 512);

  if (nb == 4) {
    gemm_bt<2><<<dim3(32, 32, 4), 256, 0, stream>>>(
        qk_t, 1024, 4096L * 1024, qk_t + 512, 1024, 4096L * 1024,
        S, 4096, 4096L * 4096, nullptr, lsum, nullptr, 0, 4096, 4096, 512);
    pv_gemm<<<dim3(64, 4, 4), 256, 0, stream>>>(
        S, 4096L * 4096, v_ws, 4096, lsum, 4096, o_t, 4096L * 512);
  } else {
    for (int b = 0; b < 4; ++b) {
      gemm_bt<2><<<dim3(32, 32, 1), 256, 0, stream>>>(
          qk_t + (long)b * 4096 * 1024, 1024, 0,
          qk_t + 512 + (long)b * 4096 * 1024, 1024, 0,
          S, 4096, 0, nullptr, lsum + b * 4096, nullptr, 0, 4096, 4096, 512);
      pv_gemm<<<dim3(64, 4, 1), 256, 0, stream>>>(
          S, 0, v_ws + (long)b * 4096, 0, lsum + b * 4096, 0,
          o_t + (long)b * 4096 * 512, 0);
    }
  }

  // out = x + Wo . o_t^T + bo   (per batch, f32)
  gemm_bt<3><<<dim3(4, 32, 4), 256, 0, stream>>>(
      Wo, 512, 0, o_t, 512, 4096L * 512, out, 4096, 512L * 4096,
      bo, nullptr, x, 512L * 4096, 512, 4096, 512);
}